// Round 10
// baseline (1319.147 us; speedup 1.0000x reference)
//
#include <hip/hip_runtime.h>

#define BB 512
#define TT 2048
#define II 8
#define HH 128
#define OO 96

typedef __attribute__((ext_vector_type(8))) short bf16x8;
typedef __attribute__((ext_vector_type(4))) float f32x4;

#define L2E 1.4426950408889634f

__device__ __forceinline__ float fast_rcp(float x) { return __builtin_amdgcn_rcpf(x); }
__device__ __forceinline__ float exp2_fast(float x) {
#if __has_builtin(__builtin_amdgcn_exp2f)
    return __builtin_amdgcn_exp2f(x);
#else
    return __expf(x * 0.6931471805599453f);
#endif
}
__device__ __forceinline__ unsigned short f2bf(float f) {
    unsigned int u = __builtin_bit_cast(unsigned int, f);
    u += 0x7fffu + ((u >> 16) & 1u);   // RNE
    return (unsigned short)(u >> 16);
}
__device__ __forceinline__ float bf2f(unsigned short h) {
    unsigned int u = ((unsigned int)h) << 16;
    return __builtin_bit_cast(float, u);
}
__device__ __forceinline__ float dot8(const float w[8], float4 a, float4 b, float acc) {
    acc = fmaf(w[0], a.x, acc); acc = fmaf(w[1], a.y, acc);
    acc = fmaf(w[2], a.z, acc); acc = fmaf(w[3], a.w, acc);
    acc = fmaf(w[4], b.x, acc); acc = fmaf(w[5], b.y, acc);
    acc = fmaf(w[6], b.z, acc); acc = fmaf(w[7], b.w, acc);
    return acc;
}

// Block = 4 waves (256 thr), ONE batch row, full T scan, grid=512 = 2 blocks/CU.
// Phase-decoupled twin recurrences: every per-CU issue count is IDENTICAL to the
// r9 best (the 384x128 GEMM per block is batch-row-invariant: 96 MFMA tiles/step,
// 32 ds_read_b128/CU/step, same VALU per lane) but the barrier cohort halves and
// the two co-resident blocks sync independently — when block A sits in its serial
// gate-tail/barrier, block B's waves issue. This attacks the ~200cyc/step idle
// residue that survived r7's lane specialization. (r1's failure was DIFFERENT:
// it kept 8 waves/block so per-CU MFMA issue doubled; here waves/block halves.)
// Wave w owns TWO j-blocks (jA=32w+col, jB=jA+16) sharing one A-fragment set
// (4 ds_read_b128 feed 24 MFMAs). 64 lanes = 2 jblk x 16 col x 2 role (r/z):
// role-split sigmoid sharing (r7 win) with partner at ln^16.
// MFMA 16x16x32 bf16, K=128 (h only; x via fp32 dot8 one iter ahead).
// A rows alternate {hi,lo} (M=2 used of 16; issue count is what matters).
// exp2-prescale: r,z by -log2e, n by +2log2e -> raw v_exp2.
// LDS: 2 bufs x 2 planes x 320B; plane set spans all 32 banks -> conflict-free
// reads. 1 barrier per step.
__global__ __launch_bounds__(256, 2) void gru_kernel(
    const float* __restrict__ x,     // [B, T, I]
    const float* __restrict__ w_ih,  // [3H, I]
    const float* __restrict__ w_hh,  // [3H, H]
    const float* __restrict__ b_ih,  // [3H]
    const float* __restrict__ b_hh,  // [3H]
    const float* __restrict__ fc_w,  // [O, H]
    const float* __restrict__ fc_b,  // [O]
    float* __restrict__ out)         // [B, O]
{
    __shared__ __align__(16) char hbuf[2 * 640];
    __shared__ __align__(16) float hfin[HH];

    const int tid  = threadIdx.x;
    const int wv   = tid >> 6;          // 0..3
    const int ln   = tid & 63;
    const int col  = ln & 15;           // C col within tile
    const int g4   = ln >> 4;           // k-subblock of A/B fragment
    const int blkB = g4 >> 1;           // 0: finalize j-block A, 1: j-block B
    const int sel  = g4 & 1;            // 0: finalize r-chain, 1: z-chain
    const int p    = ln & 1;            // A plane: even rows hi, odd rows lo
    const int jA   = 32 * wv + col;
    const int jB   = jA + 16;
    const int jS   = 32 * wv + 16 * blkB + col;   // the j this lane finalizes
    const int b0   = blockIdx.x;

    // ---- B fragments (w_hh -> bf16, weight-stationary, exp2-prescaled) ----
    auto ldfrag_hh = [&](int grow, int ks, float sc) {
        const float* rowp = w_hh + grow * HH + 32 * ks + g4 * 8;
        float4 u = *(const float4*)(rowp);
        float4 v = *(const float4*)(rowp + 4);
        bf16x8 f;
        f[0] = (short)f2bf(sc * u.x); f[1] = (short)f2bf(sc * u.y);
        f[2] = (short)f2bf(sc * u.z); f[3] = (short)f2bf(sc * u.w);
        f[4] = (short)f2bf(sc * v.x); f[5] = (short)f2bf(sc * v.y);
        f[6] = (short)f2bf(sc * v.z); f[7] = (short)f2bf(sc * v.w);
        return f;
    };

    bf16x8 bRA[4], bZA[4], bNA[4], bRB[4], bZB[4], bNB[4];
#pragma unroll
    for (int ks = 0; ks < 4; ++ks) {
        bRA[ks] = ldfrag_hh(jA, ks, -L2E);
        bZA[ks] = ldfrag_hh(HH + jA, ks, -L2E);
        bNA[ks] = ldfrag_hh(2 * HH + jA, ks, 2.0f * L2E);
        bRB[ks] = ldfrag_hh(jB, ks, -L2E);
        bZB[ks] = ldfrag_hh(HH + jB, ks, -L2E);
        bNB[ks] = ldfrag_hh(2 * HH + jB, ks, 2.0f * L2E);
    }

    // ---- w_ih rows for this lane's (jS, role) (fp32, exp2-prescaled) ----
    const int rz_row = sel ? (HH + jS) : jS;
    float wrz[8], wn[8];
    {
        const float* rzp = w_ih + rz_row * II;
        const float* r2p = w_ih + (2 * HH + jS) * II;
#pragma unroll
        for (int i = 0; i < 8; ++i) {
            wrz[i] = -L2E * rzp[i];
            wn[i]  = (2.0f * L2E) * r2p[i];
        }
    }

    const float bias_rz2 = -L2E * (b_ih[rz_row] + b_hh[rz_row]);
    const float bias_nh2 = (2.0f * L2E) * b_hh[2 * HH + jS];  // inside r*(.)
    const float bias_nx2 = (2.0f * L2E) * b_ih[2 * HH + jS];  // outside, in gx dot

    // ---- zero LDS (h=0 both buffers): 1280 B ----
    for (int i = tid; i < 320; i += 256) ((int*)hbuf)[i] = 0;
    __syncthreads();

    const char* abase = hbuf + p * 320 + g4 * 16;
    char* wbase = hbuf + (jS << 1);                   // + (1-RBUF)*640 at use
    const float* xp = x + (size_t)b0 * TT * II;

    float h0 = 0.f;
    const f32x4 zf = {0.f, 0.f, 0.f, 0.f};

    // ---- prologue: gx for t=0,1 (bias folded into dot accumulator) ----
    float grz0, gn0, grz1, gn1;
    {
        float4 xa = *(const float4*)(xp);          float4 xb = *(const float4*)(xp + 4);
        float4 xc = *(const float4*)(xp + II);     float4 xd = *(const float4*)(xp + II + 4);
        grz0 = dot8(wrz, xa, xb, bias_rz2);  gn0 = dot8(wn, xa, xb, bias_nx2);
        grz1 = dot8(wrz, xc, xd, bias_rz2);  gn1 = dot8(wn, xc, xd, bias_nx2);
    }
    float grz0n, gn0n, grz1n, gn1n;

#define MFMA_BF16 __builtin_amdgcn_mfma_f32_16x16x32_bf16

#define STEP(RBUF, GRZ, GXN, DOTS)                                              \
    {                                                                           \
        const char* ab = abase + (RBUF) * 640;                                  \
        bf16x8 a0 = *(const bf16x8*)(ab);                                       \
        bf16x8 a1 = *(const bf16x8*)(ab + 64);                                  \
        bf16x8 a2 = *(const bf16x8*)(ab + 128);                                 \
        bf16x8 a3 = *(const bf16x8*)(ab + 192);                                 \
        f32x4 aRA = MFMA_BF16(a0, bRA[0], zf, 0, 0, 0);                         \
        f32x4 aZA = MFMA_BF16(a0, bZA[0], zf, 0, 0, 0);                         \
        f32x4 aNA = MFMA_BF16(a0, bNA[0], zf, 0, 0, 0);                         \
        f32x4 aRB = MFMA_BF16(a0, bRB[0], zf, 0, 0, 0);                         \
        f32x4 aZB = MFMA_BF16(a0, bZB[0], zf, 0, 0, 0);                         \
        f32x4 aNB = MFMA_BF16(a0, bNB[0], zf, 0, 0, 0);                         \
        aRA = MFMA_BF16(a1, bRA[1], aRA, 0, 0, 0);                              \
        aZA = MFMA_BF16(a1, bZA[1], aZA, 0, 0, 0);                              \
        aNA = MFMA_BF16(a1, bNA[1], aNA, 0, 0, 0);                              \
        aRB = MFMA_BF16(a1, bRB[1], aRB, 0, 0, 0);                              \
        aZB = MFMA_BF16(a1, bZB[1], aZB, 0, 0, 0);                              \
        aNB = MFMA_BF16(a1, bNB[1], aNB, 0, 0, 0);                              \
        aRA = MFMA_BF16(a2, bRA[2], aRA, 0, 0, 0);                              \
        aZA = MFMA_BF16(a2, bZA[2], aZA, 0, 0, 0);                              \
        aNA = MFMA_BF16(a2, bNA[2], aNA, 0, 0, 0);                              \
        aRB = MFMA_BF16(a2, bRB[2], aRB, 0, 0, 0);                              \
        aZB = MFMA_BF16(a2, bZB[2], aZB, 0, 0, 0);                              \
        aNB = MFMA_BF16(a2, bNB[2], aNB, 0, 0, 0);                              \
        aRA = MFMA_BF16(a3, bRA[3], aRA, 0, 0, 0);                              \
        aZA = MFMA_BF16(a3, bZA[3], aZA, 0, 0, 0);                              \
        aNA = MFMA_BF16(a3, bNA[3], aNA, 0, 0, 0);                              \
        aRB = MFMA_BF16(a3, bRB[3], aRB, 0, 0, 0);                              \
        aZB = MFMA_BF16(a3, bZB[3], aZB, 0, 0, 0);                              \
        aNB = MFMA_BF16(a3, bNB[3], aNB, 0, 0, 0);                              \
        DOTS                                                                    \
        float cr0 = blkB ? aRB[0] : aRA[0],  cr1 = blkB ? aRB[1] : aRA[1];      \
        float cz0 = blkB ? aZB[0] : aZA[0],  cz1 = blkB ? aZB[1] : aZA[1];      \
        float cn0 = blkB ? aNB[0] : aNA[0],  cn1 = blkB ? aNB[1] : aNA[1];      \
        float c0 = sel ? cz0 : cr0,          c1 = sel ? cz1 : cr1;              \
        float grz = c0 + c1 + (GRZ);                                            \
        float s0v = fast_rcp(1.0f + exp2_fast(grz));  /* r (sel0) / z (sel1) */ \
        float zz  = __shfl_xor(s0v, 16, 64);          /* z on sel0 lanes */     \
        float gn  = cn0 + cn1 + bias_nh2;                                       \
        float t0  = fast_rcp(1.0f + exp2_fast(fmaf(s0v, gn, (GXN))));           \
        float n0  = fmaf(-2.0f, t0, 1.0f);                                      \
        h0 = fmaf(zz, h0 - n0, n0);                   /* valid on sel0 lanes */ \
        if (sel == 0) {                                                         \
            char* w_ = wbase + (1 - (RBUF)) * 640;                              \
            unsigned short s0 = f2bf(h0);                                       \
            *(unsigned short*)(w_)       = s0;                                  \
            *(unsigned short*)(w_ + 320) = f2bf(h0 - bf2f(s0));                 \
        }                                                                       \
        __syncthreads();                                                        \
    }

    for (int it = 0; it < TT / 2; ++it) {
        // prefetch x(t+2), x(t+3) -- consumed by DOTS (2 per STEP, balanced)
        int t2 = 2 * it + 2; if (t2 > TT - 1) t2 = TT - 1;
        int t3 = t2 + 1;     if (t3 > TT - 1) t3 = TT - 1;
        float4 pa = *(const float4*)(xp + (size_t)t2 * II);
        float4 pb = *(const float4*)(xp + (size_t)t2 * II + 4);
        float4 pc = *(const float4*)(xp + (size_t)t3 * II);
        float4 pd = *(const float4*)(xp + (size_t)t3 * II + 4);

        STEP(0, grz0, gn0, {                    // even t: read buf0, write buf1
            grz0n = dot8(wrz, pa, pb, bias_rz2);
            gn0n  = dot8(wn,  pa, pb, bias_nx2);
        })
        STEP(1, grz1, gn1, {                    // odd  t: read buf1, write buf0
            grz1n = dot8(wrz, pc, pd, bias_rz2);
            gn1n  = dot8(wn,  pc, pd, bias_nx2);
        })
        grz0 = grz0n; gn0 = gn0n;
        grz1 = grz1n; gn1 = gn1n;
    }
#undef STEP
#undef MFMA_BF16

    // ---- epilogue FC on fp32 h ----
    if (sel == 0) hfin[jS] = h0;
    __syncthreads();

    if (tid < OO) {
        const float4* hf = (const float4*)(&hfin[0]);
        const float4* wp = (const float4*)(fc_w + tid * HH);
        float acc = fc_b[tid];
#pragma unroll 8
        for (int v = 0; v < HH / 4; ++v) {
            float4 w4 = wp[v];
            float4 h4 = hf[v];
            acc = fmaf(w4.x, h4.x, acc); acc = fmaf(w4.y, h4.y, acc);
            acc = fmaf(w4.z, h4.z, acc); acc = fmaf(w4.w, h4.w, acc);
        }
        out[(size_t)b0 * OO + tid] = acc;
    }
}

extern "C" void kernel_launch(void* const* d_in, const int* in_sizes, int n_in,
                              void* d_out, int out_size, void* d_ws, size_t ws_size,
                              hipStream_t stream) {
    const float* x    = (const float*)d_in[0];
    const float* w_ih = (const float*)d_in[1];
    const float* w_hh = (const float*)d_in[2];
    const float* b_ih = (const float*)d_in[3];
    const float* b_hh = (const float*)d_in[4];
    const float* fc_w = (const float*)d_in[5];
    const float* fc_b = (const float*)d_in[6];
    float* out = (float*)d_out;

    gru_kernel<<<BB, 256, 0, stream>>>(x, w_ih, w_hh, b_ih, b_hh, fc_w, fc_b, out);
}